// Round 4
// baseline (19406.378 us; speedup 1.0000x reference)
//
#include <hip/hip_runtime.h>
#include <stdint.h>

#define Hdim 512
#define Bsz 64
#define Tlen 1024
#define RING 8
#define BH (Bsz * Hdim)

typedef __attribute__((ext_vector_type(8))) short short8;
typedef __attribute__((ext_vector_type(4))) float f32x4;

__device__ __forceinline__ short f2bf(float f) {
  uint32_t u = __float_as_uint(f);
  u += 0x7fffu + ((u >> 16) & 1u);   // RNE
  return (short)(u >> 16);
}

__device__ __forceinline__ f32x4 mfma16(short8 a, short8 b, f32x4 c) {
  return __builtin_amdgcn_mfma_f32_16x16x32_bf16(a, b, c, 0, 0, 0);
}

// Wave-parallel flag poll: lane l watches f[l]; exit when ALL 64 flags >= tgt.
__device__ __forceinline__ void wait_flags(const uint32_t* f, uint32_t tgt, int lane) {
  uint32_t it = 0;
  for (;;) {
    uint32_t v = __hip_atomic_load(f + lane, __ATOMIC_RELAXED, __HIP_MEMORY_SCOPE_AGENT);
    if (__all((int)(v >= tgt))) break;
    if (++it > (1u << 20)) break;  // failsafe against hang
  }
}

__global__ void out_init(float* out, const float* bout) {
  int i = blockIdx.x * 256 + threadIdx.x;
  if (i < Bsz * Tlen) out[i] = bout[0];
}

// ---- weight pack: unchanged from R1 (verified correct) ----
__global__ void pack_kernel(const float* __restrict__ Whh0,
                            const float* __restrict__ Wih1, const float* __restrict__ Whh1,
                            const float* __restrict__ Wih2, const float* __restrict__ Whh2,
                            short* __restrict__ Bpack) {
  int ch = blockIdx.x * 256 + threadIdx.x;
  const int L0C = 64 * 16 * 2 * 64;
  const int L12C = 64 * 32 * 2 * 64;
  if (ch >= L0C + 2 * L12C) return;
  int layer, rel, KS;
  const float* Wih;
  const float* Whh;
  if (ch < L0C) { layer = 0; rel = ch; KS = 16; Wih = nullptr; Whh = Whh0; }
  else if (ch < L0C + L12C) { layer = 1; rel = ch - L0C; KS = 32; Wih = Wih1; Whh = Whh1; }
  else { layer = 2; rel = ch - L0C - L12C; KS = 32; Wih = Wih2; Whh = Whh2; }
  int lane = rel & 63;
  int nt = (rel >> 6) & 1;
  int rest = rel >> 7;
  int ks = rest % KS;
  int wg = rest / KS;
  int col = nt * 16 + (lane & 15);
  int row = (col >> 3) * Hdim + wg * 8 + (col & 7);
  int kbase = ks * 32 + (lane >> 4) * 8;
  short8 v;
#pragma unroll
  for (int e = 0; e < 8; ++e) {
    int k = kbase + e;
    float w;
    if (layer == 0) w = Whh[row * Hdim + k];
    else w = (k < Hdim) ? Wih[row * Hdim + k] : Whh[row * Hdim + (k - Hdim)];
    v[e] = f2bf(w);
  }
  ((short8*)Bpack)[ch] = v;
}

__global__ __launch_bounds__(256, 1)
void lstm_persist(const float* __restrict__ x,
                  const float* __restrict__ Wih0v,
                  const float* __restrict__ bih0, const float* __restrict__ bhh0,
                  const float* __restrict__ bih1, const float* __restrict__ bhh1,
                  const float* __restrict__ bih2, const float* __restrict__ bhh2,
                  const float* __restrict__ Wout,
                  const short* __restrict__ Bpack,
                  short* __restrict__ rings,
                  uint32_t* __restrict__ flags,
                  float* __restrict__ out) {
  const int blk = blockIdx.x;
  const int layer = blk >> 6;
  const int wg = blk & 63;
  const int tid = threadIdx.x;
  const int lane = tid & 63;
  const int wave = tid >> 6;  // 0..3, all compute
  const int bm = wave * 16;

  // ---- persistent B fragments: plain loads + empty-asm keepalive pin ----
  short8 bw[32][2];
  {
    const short8* bp = (const short8*)Bpack;
    if (layer == 0) {
      const int base = 0;
#pragma unroll
      for (int ks = 0; ks < 16; ++ks) {
        bw[ks][0] = bp[base + ((wg * 16 + ks) * 2 + 0) * 64 + lane];
        bw[ks][1] = bp[base + ((wg * 16 + ks) * 2 + 1) * 64 + lane];
        asm volatile("" : "+v"(bw[ks][0]), "+v"(bw[ks][1]));
      }
    } else {
      const int base = (layer == 1) ? 131072 : 393216;
#pragma unroll
      for (int ks = 0; ks < 32; ++ks) {
        bw[ks][0] = bp[base + ((wg * 32 + ks) * 2 + 0) * 64 + lane];
        bw[ks][1] = bp[base + ((wg * 32 + ks) * 2 + 1) * 64 + lane];
        asm volatile("" : "+v"(bw[ks][0]), "+v"(bw[ks][1]));
      }
    }
  }

  const float* bih = (layer == 0) ? bih0 : (layer == 1 ? bih1 : bih2);
  const float* bhh = (layer == 0) ? bhh0 : (layer == 1 ? bhh1 : bhh2);
  const int col0 = (lane & 15);
  const int col1 = 16 + (lane & 15);
  const int row0 = (col0 >> 3) * Hdim + wg * 8 + (col0 & 7);
  const int row1 = (col1 >> 3) * Hdim + wg * 8 + (col1 & 7);
  const float bias0 = bih[row0] + bhh[row0];
  const float bias1 = bih[row1] + bhh[row1];
  float xw0 = 0.f, xw1 = 0.f, woutd = 0.f;
  if (layer == 0) { xw0 = Wih0v[row0]; xw1 = Wih0v[row1]; }
  if (layer == 2) woutd = Wout[wg * 8 + (lane & 7)];

  uint32_t* flagsO = flags + layer * 64;
  const uint32_t* flagsP = flags + (layer - 1) * 64;  // deref guarded by layer>0
  const uint32_t* flagsN = flags + (layer + 1) * 64;  // deref guarded by layer<2
  short* ringL = rings + layer * (RING * BH);
  const short* ringP = rings + (layer - 1) * (RING * BH);

  const int aoff = (bm + (lane & 15)) * Hdim + (lane >> 4) * 8;
  const int bX = bm + 4 * (lane >> 4);

  float c[4] = {0.f, 0.f, 0.f, 0.f};

  for (int t = 0; t < Tlen; ++t) {
    // ---- phase 1: cross-layer input (pipeline slack) ----
    f32x4 acc0 = {bias0, bias0, bias0, bias0};
    f32x4 acc1 = {bias1, bias1, bias1, bias1};
    if (layer > 0) {
      wait_flags(flagsP, (uint32_t)(t + 1), lane);
      __builtin_amdgcn_fence(__ATOMIC_ACQUIRE, "agent");
      const short* xin = ringP + (t & (RING - 1)) * BH;
      short8 ap[16];
#pragma unroll
      for (int ks = 0; ks < 16; ++ks) ap[ks] = *(const short8*)(xin + aoff + ks * 32);
#pragma unroll
      for (int ks = 0; ks < 16; ++ks) {
        acc0 = mfma16(ap[ks], bw[ks][0], acc0);
        acc1 = mfma16(ap[ks], bw[ks][1], acc1);
      }
    } else if (t > 0) {
#pragma unroll
      for (int r = 0; r < 4; ++r) {
        float xv = x[(bX + r) * Tlen + (t - 1)];  // DELAY=1
        acc0[r] += xw0 * xv;
        acc1[r] += xw1 * xv;
      }
    }

    // ---- phase 2: own-layer recurrence (critical path) ----
    if (t > 0) wait_flags(flagsO, (uint32_t)t, lane);
    if (layer < 2 && t >= RING) wait_flags(flagsN, (uint32_t)(t + 1 - RING), lane);

    if (t > 0) {
      __builtin_amdgcn_fence(__ATOMIC_ACQUIRE, "agent");
      const short* hin = ringL + ((t - 1) & (RING - 1)) * BH;
      short8 ar[16];
#pragma unroll
      for (int ks = 0; ks < 16; ++ks) ar[ks] = *(const short8*)(hin + aoff + ks * 32);
      if (layer == 0) {
#pragma unroll
        for (int ks = 0; ks < 16; ++ks) {
          acc0 = mfma16(ar[ks], bw[ks][0], acc0);
          acc1 = mfma16(ar[ks], bw[ks][1], acc1);
        }
      } else {
#pragma unroll
        for (int ks = 0; ks < 16; ++ks) {
          acc0 = mfma16(ar[ks], bw[16 + ks][0], acc0);
          acc1 = mfma16(ar[ks], bw[16 + ks][1], acc1);
        }
      }
    }

    // ---- activations / state update / publish h (R1-identical) ----
    short* hout = ringL + (t & (RING - 1)) * BH;
    float parts[4];
#pragma unroll
    for (int r = 0; r < 4; ++r) {
      float a0 = acc0[r], a1 = acc1[r];
      float p0 = __shfl_xor(a0, 8);
      float p1 = __shfl_xor(a1, 8);
      float iv = 1.f / (1.f + __expf(-a0));
      float fv = 1.f / (1.f + __expf(-p0));
      float gv = tanhf(a1);
      float ov = 1.f / (1.f + __expf(-p1));
      c[r] = fv * c[r] + iv * gv;
      float hv = ov * tanhf(c[r]);
      if ((lane & 8) == 0) hout[(bX + r) * Hdim + wg * 8 + (lane & 7)] = f2bf(hv);
      parts[r] = hv * woutd;
    }
    if (layer == 2) {
#pragma unroll
      for (int r = 0; r < 4; ++r) {
        parts[r] += __shfl_xor(parts[r], 1);
        parts[r] += __shfl_xor(parts[r], 2);
        parts[r] += __shfl_xor(parts[r], 4);
        if ((lane & 15) == 0) atomicAdd(out + (bX + r) * Tlen + t, parts[r]);
      }
    }

    // ---- release + publish flag (R1 pattern, store instead of RMW) ----
    __syncthreads();
    if (tid == 0) {
      __builtin_amdgcn_fence(__ATOMIC_RELEASE, "agent");
      __hip_atomic_store(flagsO + wg, (uint32_t)(t + 1), __ATOMIC_RELAXED,
                         __HIP_MEMORY_SCOPE_AGENT);
    }
  }
}

extern "C" void kernel_launch(void* const* d_in, const int* in_sizes, int n_in,
                              void* d_out, int out_size, void* d_ws, size_t ws_size,
                              hipStream_t stream) {
  const float* x    = (const float*)d_in[0];
  const float* Wih0 = (const float*)d_in[1];
  const float* Whh0 = (const float*)d_in[2];
  const float* bih0 = (const float*)d_in[3];
  const float* bhh0 = (const float*)d_in[4];
  const float* Wih1 = (const float*)d_in[5];
  const float* Whh1 = (const float*)d_in[6];
  const float* bih1 = (const float*)d_in[7];
  const float* bhh1 = (const float*)d_in[8];
  const float* Wih2 = (const float*)d_in[9];
  const float* Whh2 = (const float*)d_in[10];
  const float* bih2 = (const float*)d_in[11];
  const float* bhh2 = (const float*)d_in[12];
  const float* Wout = (const float*)d_in[13];
  const float* bout = (const float*)d_in[14];

  char* ws = (char*)d_ws;
  short* Bpack    = (short*)ws;                          // 10,485,760 B
  short* rings    = (short*)(ws + 10485760);             // 1,572,864 B
  uint32_t* flags = (uint32_t*)(ws + 12058624);          // 768 B (total ~12.06 MB, R1-proven)
  float* out      = (float*)d_out;

  hipMemsetAsync(flags, 0, 3 * 64 * sizeof(uint32_t), stream);
  out_init<<<(Bsz * Tlen + 255) / 256, 256, 0, stream>>>(out, bout);
  pack_kernel<<<2560, 256, 0, stream>>>(Whh0, Wih1, Whh1, Wih2, Whh2, Bpack);
  lstm_persist<<<192, 256, 0, stream>>>(x, Wih0, bih0, bhh0, bih1, bhh1, bih2, bhh2,
                                        Wout, Bpack, rings, flags, out);
}

// Round 5
// 11413.637 us; speedup vs baseline: 1.7003x; 1.7003x over previous
//
#include <hip/hip_runtime.h>
#include <stdint.h>

#define Hdim 512
#define Bsz 64
#define Tlen 1024
#define RING 8
#define BH (Bsz * Hdim)

typedef __attribute__((ext_vector_type(8))) short short8;
typedef __attribute__((ext_vector_type(4))) float f32x4;
typedef unsigned long long u64;
struct u64x2 { u64 lo, hi; };

__device__ __forceinline__ short f2bf(float f) {
  uint32_t u = __float_as_uint(f);
  u += 0x7fffu + ((u >> 16) & 1u);   // RNE
  return (short)(u >> 16);
}

__device__ __forceinline__ f32x4 mfma16(short8 a, short8 b, f32x4 c) {
  return __builtin_amdgcn_mfma_f32_16x16x32_bf16(a, b, c, 0, 0, 0);
}

// LLC-coherent 16B ring read as two relaxed agent-scope 8B atomic loads
// (compile to global_load_dwordx2 sc0 sc1 — per-op coherence, NO bulk cache ops).
__device__ __forceinline__ short8 ring_ld16(const short* p) {
  u64x2 u;
  u.lo = __hip_atomic_load((const u64*)p,     __ATOMIC_RELAXED, __HIP_MEMORY_SCOPE_AGENT);
  u.hi = __hip_atomic_load((const u64*)p + 1, __ATOMIC_RELAXED, __HIP_MEMORY_SCOPE_AGENT);
  return __builtin_bit_cast(short8, u);
}

__device__ __forceinline__ void vm_wait0() {
  asm volatile("s_waitcnt vmcnt(0)" ::: "memory");
  __builtin_amdgcn_sched_barrier(0);
}

// Wave-parallel flag poll: lane l watches f[l]; exit when ALL 64 flags >= tgt.
__device__ __forceinline__ void wait_flags(const uint32_t* f, uint32_t tgt, int lane) {
  uint32_t it = 0;
  for (;;) {
    uint32_t v = __hip_atomic_load(f + lane, __ATOMIC_RELAXED, __HIP_MEMORY_SCOPE_AGENT);
    if (__all((int)(v >= tgt))) break;
    if (++it > (1u << 20)) break;  // failsafe against hang
  }
}

__global__ void out_init(float* out, const float* bout) {
  int i = blockIdx.x * 256 + threadIdx.x;
  if (i < Bsz * Tlen) out[i] = bout[0];
}

// ---- weight pack: unchanged from R1 (verified correct) ----
__global__ void pack_kernel(const float* __restrict__ Whh0,
                            const float* __restrict__ Wih1, const float* __restrict__ Whh1,
                            const float* __restrict__ Wih2, const float* __restrict__ Whh2,
                            short* __restrict__ Bpack) {
  int ch = blockIdx.x * 256 + threadIdx.x;
  const int L0C = 64 * 16 * 2 * 64;
  const int L12C = 64 * 32 * 2 * 64;
  if (ch >= L0C + 2 * L12C) return;
  int layer, rel, KS;
  const float* Wih;
  const float* Whh;
  if (ch < L0C) { layer = 0; rel = ch; KS = 16; Wih = nullptr; Whh = Whh0; }
  else if (ch < L0C + L12C) { layer = 1; rel = ch - L0C; KS = 32; Wih = Wih1; Whh = Whh1; }
  else { layer = 2; rel = ch - L0C - L12C; KS = 32; Wih = Wih2; Whh = Whh2; }
  int lane = rel & 63;
  int nt = (rel >> 6) & 1;
  int rest = rel >> 7;
  int ks = rest % KS;
  int wg = rest / KS;
  int col = nt * 16 + (lane & 15);
  int row = (col >> 3) * Hdim + wg * 8 + (col & 7);
  int kbase = ks * 32 + (lane >> 4) * 8;
  short8 v;
#pragma unroll
  for (int e = 0; e < 8; ++e) {
    int k = kbase + e;
    float w;
    if (layer == 0) w = Whh[row * Hdim + k];
    else w = (k < Hdim) ? Wih[row * Hdim + k] : Whh[row * Hdim + (k - Hdim)];
    v[e] = f2bf(w);
  }
  ((short8*)Bpack)[ch] = v;
}

__global__ __launch_bounds__(256, 1)
void lstm_persist(const float* __restrict__ x,
                  const float* __restrict__ Wih0v,
                  const float* __restrict__ bih0, const float* __restrict__ bhh0,
                  const float* __restrict__ bih1, const float* __restrict__ bhh1,
                  const float* __restrict__ bih2, const float* __restrict__ bhh2,
                  const float* __restrict__ Wout,
                  const short* __restrict__ Bpack,
                  short* __restrict__ rings,
                  uint32_t* __restrict__ flags,
                  float* __restrict__ out) {
  const int blk = blockIdx.x;
  const int layer = blk >> 6;
  const int wg = blk & 63;
  const int tid = threadIdx.x;
  const int lane = tid & 63;
  const int wave = tid >> 6;  // 0..3, all compute
  const int bm = wave * 16;

  __shared__ short hbuf[Bsz][8];  // h staging: [batch][dim-within-block]

  // ---- persistent B fragments: plain loads + keepalive pin (R4-proven) ----
  short8 bw[32][2];
  {
    const short8* bp = (const short8*)Bpack;
    if (layer == 0) {
#pragma unroll
      for (int ks = 0; ks < 16; ++ks) {
        bw[ks][0] = bp[((wg * 16 + ks) * 2 + 0) * 64 + lane];
        bw[ks][1] = bp[((wg * 16 + ks) * 2 + 1) * 64 + lane];
        asm volatile("" : "+v"(bw[ks][0]), "+v"(bw[ks][1]));
      }
    } else {
      const int base = (layer == 1) ? 131072 : 393216;
#pragma unroll
      for (int ks = 0; ks < 32; ++ks) {
        bw[ks][0] = bp[base + ((wg * 32 + ks) * 2 + 0) * 64 + lane];
        bw[ks][1] = bp[base + ((wg * 32 + ks) * 2 + 1) * 64 + lane];
        asm volatile("" : "+v"(bw[ks][0]), "+v"(bw[ks][1]));
      }
    }
  }

  const float* bih = (layer == 0) ? bih0 : (layer == 1 ? bih1 : bih2);
  const float* bhh = (layer == 0) ? bhh0 : (layer == 1 ? bhh1 : bhh2);
  const int col0 = (lane & 15);
  const int col1 = 16 + (lane & 15);
  const int row0 = (col0 >> 3) * Hdim + wg * 8 + (col0 & 7);
  const int row1 = (col1 >> 3) * Hdim + wg * 8 + (col1 & 7);
  const float bias0 = bih[row0] + bhh[row0];
  const float bias1 = bih[row1] + bhh[row1];
  float xw0 = 0.f, xw1 = 0.f, woutd = 0.f;
  if (layer == 0) { xw0 = Wih0v[row0]; xw1 = Wih0v[row1]; }
  if (layer == 2) woutd = Wout[wg * 8 + (lane & 7)];

  uint32_t* flagsO = flags + layer * 64;
  const uint32_t* flagsP = flags + (layer - 1) * 64;  // deref guarded by layer>0
  const uint32_t* flagsN = flags + (layer + 1) * 64;  // deref guarded by layer<2
  short* ringL = rings + layer * (RING * BH);
  const short* ringP = rings + (layer - 1) * (RING * BH);

  const int aoff = (bm + (lane & 15)) * Hdim + (lane >> 4) * 8;
  const int bX = bm + 4 * (lane >> 4);

  float c[4] = {0.f, 0.f, 0.f, 0.f};

  for (int t = 0; t < Tlen; ++t) {
    // ---- phase 1: cross-layer input (pipeline slack) ----
    f32x4 acc0 = {bias0, bias0, bias0, bias0};
    f32x4 acc1 = {bias1, bias1, bias1, bias1};
    if (layer > 0) {
      wait_flags(flagsP, (uint32_t)(t + 1), lane);
      const short* xin = ringP + (t & (RING - 1)) * BH;
      short8 ap[16];
#pragma unroll
      for (int ks = 0; ks < 16; ++ks) ap[ks] = ring_ld16(xin + aoff + ks * 32);
#pragma unroll
      for (int ks = 0; ks < 16; ++ks) {
        acc0 = mfma16(ap[ks], bw[ks][0], acc0);
        acc1 = mfma16(ap[ks], bw[ks][1], acc1);
      }
    } else if (t > 0) {
#pragma unroll
      for (int r = 0; r < 4; ++r) {
        float xv = x[(bX + r) * Tlen + (t - 1)];  // DELAY=1
        acc0[r] += xw0 * xv;
        acc1[r] += xw1 * xv;
      }
    }

    // ---- phase 2: own-layer recurrence (critical path) ----
    if (t > 0) wait_flags(flagsO, (uint32_t)t, lane);
    if (layer < 2 && t >= RING) wait_flags(flagsN, (uint32_t)(t + 1 - RING), lane);

    if (t > 0) {
      const short* hin = ringL + ((t - 1) & (RING - 1)) * BH;
      short8 ar[16];
#pragma unroll
      for (int ks = 0; ks < 16; ++ks) ar[ks] = ring_ld16(hin + aoff + ks * 32);
      if (layer == 0) {
#pragma unroll
        for (int ks = 0; ks < 16; ++ks) {
          acc0 = mfma16(ar[ks], bw[ks][0], acc0);
          acc1 = mfma16(ar[ks], bw[ks][1], acc1);
        }
      } else {
#pragma unroll
        for (int ks = 0; ks < 16; ++ks) {
          acc0 = mfma16(ar[ks], bw[16 + ks][0], acc0);
          acc1 = mfma16(ar[ks], bw[16 + ks][1], acc1);
        }
      }
    }

    // ---- activations / state update ----
    float parts[4];
#pragma unroll
    for (int r = 0; r < 4; ++r) {
      float a0 = acc0[r], a1 = acc1[r];
      float p0 = __shfl_xor(a0, 8);
      float p1 = __shfl_xor(a1, 8);
      float iv = 1.f / (1.f + __expf(-a0));
      float fv = 1.f / (1.f + __expf(-p0));
      float gv = tanhf(a1);
      float ov = 1.f / (1.f + __expf(-p1));
      c[r] = fv * c[r] + iv * gv;
      float hv = ov * tanhf(c[r]);
      if ((lane & 8) == 0) hbuf[bX + r][lane & 7] = f2bf(hv);
      parts[r] = hv * woutd;
    }
    if (layer == 2) {
#pragma unroll
      for (int r = 0; r < 4; ++r) {
        parts[r] += __shfl_xor(parts[r], 1);
        parts[r] += __shfl_xor(parts[r], 2);
        parts[r] += __shfl_xor(parts[r], 4);
        if ((lane & 15) == 0) atomicAdd(out + (bX + r) * Tlen + t, parts[r]);
      }
    }

    // ---- publish h (wave 0: LLC atomic stores) + flag ----
    __syncthreads();  // hbuf complete
    if (wave == 0) {
      short* hout = ringL + (t & (RING - 1)) * BH;
      int b = lane;  // one batch row per lane
      u64x2 u;
      u.lo = ((const u64*)&hbuf[b][0])[0];
      u.hi = ((const u64*)&hbuf[b][0])[1];
      u64* dst = (u64*)(hout + (size_t)b * Hdim + wg * 8);
      __hip_atomic_store(dst,     u.lo, __ATOMIC_RELAXED, __HIP_MEMORY_SCOPE_AGENT);
      __hip_atomic_store(dst + 1, u.hi, __ATOMIC_RELAXED, __HIP_MEMORY_SCOPE_AGENT);
      vm_wait0();  // h stores acked at coherence point before flag
      if (lane == 0)
        __hip_atomic_store(flagsO + wg, (uint32_t)(t + 1), __ATOMIC_RELAXED,
                           __HIP_MEMORY_SCOPE_AGENT);
    }
  }
}

extern "C" void kernel_launch(void* const* d_in, const int* in_sizes, int n_in,
                              void* d_out, int out_size, void* d_ws, size_t ws_size,
                              hipStream_t stream) {
  const float* x    = (const float*)d_in[0];
  const float* Wih0 = (const float*)d_in[1];
  const float* Whh0 = (const float*)d_in[2];
  const float* bih0 = (const float*)d_in[3];
  const float* bhh0 = (const float*)d_in[4];
  const float* Wih1 = (const float*)d_in[5];
  const float* Whh1 = (const float*)d_in[6];
  const float* bih1 = (const float*)d_in[7];
  const float* bhh1 = (const float*)d_in[8];
  const float* Wih2 = (const float*)d_in[9];
  const float* Whh2 = (const float*)d_in[10];
  const float* bih2 = (const float*)d_in[11];
  const float* bhh2 = (const float*)d_in[12];
  const float* Wout = (const float*)d_in[13];
  const float* bout = (const float*)d_in[14];

  char* ws = (char*)d_ws;
  short* Bpack    = (short*)ws;                          // 10,485,760 B
  short* rings    = (short*)(ws + 10485760);             // 1,572,864 B
  uint32_t* flags = (uint32_t*)(ws + 12058624);          // 768 B (total ~12.06 MB, proven)
  float* out      = (float*)d_out;

  hipMemsetAsync(flags, 0, 3 * 64 * sizeof(uint32_t), stream);
  out_init<<<(Bsz * Tlen + 255) / 256, 256, 0, stream>>>(out, bout);
  pack_kernel<<<2560, 256, 0, stream>>>(Whh0, Wih1, Whh1, Wih2, Whh2, Bpack);
  lstm_persist<<<192, 256, 0, stream>>>(x, Wih0, bih0, bhh0, bih1, bhh1, bih2, bhh2,
                                        Wout, Bpack, rings, flags, out);
}

// Round 6
// 10231.414 us; speedup vs baseline: 1.8967x; 1.1155x over previous
//
#include <hip/hip_runtime.h>
#include <stdint.h>

#define Hdim 512
#define Bsz 64
#define Tlen 1024
#define RING 8
#define NGRP 4            // batch groups of 16 rows
#define NDB 16            // dim-blocks per layer (32 h-dims each)
#define GR (RING * 16 * Hdim)  // ring shorts per (layer,group)

typedef __attribute__((ext_vector_type(8))) short short8;
typedef __attribute__((ext_vector_type(4))) float f32x4;
typedef unsigned long long u64;
struct u64x2 { u64 lo, hi; };

__device__ __forceinline__ short f2bf(float f) {
  uint32_t u = __float_as_uint(f);
  u += 0x7fffu + ((u >> 16) & 1u);   // RNE
  return (short)(u >> 16);
}

__device__ __forceinline__ f32x4 mfma16(short8 a, short8 b, f32x4 c) {
  return __builtin_amdgcn_mfma_f32_16x16x32_bf16(a, b, c, 0, 0, 0);
}

// LLC-coherent 16B ring read as two relaxed agent-scope 8B atomic loads (R5-proven).
__device__ __forceinline__ short8 ring_ld16(const short* p) {
  u64x2 u;
  u.lo = __hip_atomic_load((const u64*)p,     __ATOMIC_RELAXED, __HIP_MEMORY_SCOPE_AGENT);
  u.hi = __hip_atomic_load((const u64*)p + 1, __ATOMIC_RELAXED, __HIP_MEMORY_SCOPE_AGENT);
  return __builtin_bit_cast(short8, u);
}

__device__ __forceinline__ void vm_wait0() {
  asm volatile("s_waitcnt vmcnt(0)" ::: "memory");
  __builtin_amdgcn_sched_barrier(0);
}

// Poll: each lane watches *pp until >= tgt; exit when all lanes satisfied.
__device__ __forceinline__ void wait_multi(const uint32_t* pp, uint32_t tgt) {
  uint32_t it = 0;
  for (;;) {
    uint32_t v = __hip_atomic_load(pp, __ATOMIC_RELAXED, __HIP_MEMORY_SCOPE_AGENT);
    if (__all((int)(v >= tgt))) break;
    if (++it > (1u << 20)) break;  // failsafe against hang
  }
}

__global__ void out_init(float* out, const float* bout) {
  int i = blockIdx.x * 256 + threadIdx.x;
  if (i < Bsz * Tlen) out[i] = bout[0];
}

// Pack weights into MFMA B-fragment order, bf16.
// Chunk idx: [L0: (d*4+w)(64) x ks(16) x nt(2) x lane(64)][L1: (d*4+w) x 32 x 2 x 64][L2: same]
// col = nt*16+(lane&15); gate = col>>3; row = gate*512 + d*32 + w*8 + (col&7);
// k = ks*32 + (lane>>4)*8 + e.  k<512 -> Wih (L1/L2), k>=512 -> Whh[k-512]. L0: all Whh0.
__global__ void pack_kernel(const float* __restrict__ Whh0,
                            const float* __restrict__ Wih1, const float* __restrict__ Whh1,
                            const float* __restrict__ Wih2, const float* __restrict__ Whh2,
                            short* __restrict__ Bpack) {
  int ch = blockIdx.x * 256 + threadIdx.x;
  const int L0C = 64 * 16 * 2 * 64;
  const int L12C = 64 * 32 * 2 * 64;
  if (ch >= L0C + 2 * L12C) return;
  int layer, rel, KS;
  const float* Wih;
  const float* Whh;
  if (ch < L0C) { layer = 0; rel = ch; KS = 16; Wih = nullptr; Whh = Whh0; }
  else if (ch < L0C + L12C) { layer = 1; rel = ch - L0C; KS = 32; Wih = Wih1; Whh = Whh1; }
  else { layer = 2; rel = ch - L0C - L12C; KS = 32; Wih = Wih2; Whh = Whh2; }
  int lane = rel & 63;
  int nt = (rel >> 6) & 1;
  int rest = rel >> 7;          // (d*4+w)*KS + ks
  int ks = rest % KS;
  int dw = rest / KS;
  int w = dw & 3;
  int d = dw >> 2;
  int col = nt * 16 + (lane & 15);
  int row = (col >> 3) * Hdim + d * 32 + w * 8 + (col & 7);
  int kbase = ks * 32 + (lane >> 4) * 8;
  short8 v;
#pragma unroll
  for (int e = 0; e < 8; ++e) {
    int k = kbase + e;
    float wt;
    if (layer == 0) wt = Whh[row * Hdim + k];
    else wt = (k < Hdim) ? Wih[row * Hdim + k] : Whh[row * Hdim + (k - Hdim)];
    v[e] = f2bf(wt);
  }
  ((short8*)Bpack)[ch] = v;
}

__global__ __launch_bounds__(256, 1)
void lstm_persist(const float* __restrict__ x,
                  const float* __restrict__ Wih0v,
                  const float* __restrict__ bih0, const float* __restrict__ bhh0,
                  const float* __restrict__ bih1, const float* __restrict__ bhh1,
                  const float* __restrict__ bih2, const float* __restrict__ bhh2,
                  const float* __restrict__ Wout,
                  const short* __restrict__ Bpack,
                  short* __restrict__ rings,
                  uint32_t* __restrict__ flags,
                  float* __restrict__ out) {
  const int blk = blockIdx.x;
  const int layer = blk >> 6;          // 0..2
  const int g = (blk >> 4) & 3;        // batch group (16 rows)
  const int d = blk & 15;              // dim-block (32 h-dims)
  const int tid = threadIdx.x;
  const int lane = tid & 63;
  const int wave = tid >> 6;           // 0..3 = N-slice (8 h-dims, 4 gates)

  __shared__ short hbuf[16][32];       // [group-row][dim within block]
  __shared__ float pbuf[4][16];        // out-head partials [wave][group-row]

  // ---- persistent B fragments: plain loads + keepalive pin (R4/R5-proven) ----
  short8 bw[32][2];
  {
    const short8* bp = (const short8*)Bpack;
    if (layer == 0) {
#pragma unroll
      for (int ks = 0; ks < 16; ++ks) {
        bw[ks][0] = bp[((((d * 4 + wave) * 16 + ks) * 2 + 0) * 64) + lane];
        bw[ks][1] = bp[((((d * 4 + wave) * 16 + ks) * 2 + 1) * 64) + lane];
        asm volatile("" : "+v"(bw[ks][0]), "+v"(bw[ks][1]));
      }
    } else {
      const int base = (layer == 1) ? 131072 : 393216;
#pragma unroll
      for (int ks = 0; ks < 32; ++ks) {
        bw[ks][0] = bp[base + (((d * 4 + wave) * 32 + ks) * 2 + 0) * 64 + lane];
        bw[ks][1] = bp[base + (((d * 4 + wave) * 32 + ks) * 2 + 1) * 64 + lane];
        asm volatile("" : "+v"(bw[ks][0]), "+v"(bw[ks][1]));
      }
    }
  }

  const float* bih = (layer == 0) ? bih0 : (layer == 1 ? bih1 : bih2);
  const float* bhh = (layer == 0) ? bhh0 : (layer == 1 ? bhh1 : bhh2);
  const int dimb = d * 32 + wave * 8 + (lane & 7);           // h-dim for this lane's cols
  const int row0 = (((lane & 15) >> 3)) * Hdim + dimb;       // gates i/f
  const int row1 = (((lane & 15) >> 3) + 2) * Hdim + dimb;   // gates g/o
  const float bias0 = bih[row0] + bhh[row0];
  const float bias1 = bih[row1] + bhh[row1];
  float xw0 = 0.f, xw1 = 0.f, woutd = 0.f;
  if (layer == 0) { xw0 = Wih0v[row0]; xw1 = Wih0v[row1]; }
  if (layer == 2) woutd = Wout[dimb];

  // flags: 32 words per (layer,group), word d
  uint32_t* flagsO = flags + (layer * 4 + g) * 32;
  const uint32_t* flagsP = flags + ((layer - 1) * 4 + g) * 32;  // guarded layer>0
  const uint32_t* flagsN = flags + ((layer + 1) * 4 + g) * 32;  // guarded layer<2
  short* ringLG = rings + (layer * 4 + g) * GR;
  const short* ringPG = rings + ((layer - 1) * 4 + g) * GR;

  // merged phase-2 poll: lanes 0-15 own flags (tgt t); lanes 32-47 next-layer
  // backpressure (tgt t+1-RING, clamped); others trivially true (tgt 0).
  const uint32_t* pollP2;
  int pollMode;  // 0 = own, 1 = backpressure, 2 = trivial
  if (lane < 16) { pollP2 = flagsO + lane; pollMode = 0; }
  else if (lane >= 32 && lane < 48 && layer < 2) { pollP2 = flagsN + (lane - 32); pollMode = 1; }
  else { pollP2 = flagsO; pollMode = 2; }

  const int aoff = (lane & 15) * Hdim + (lane >> 4) * 8;  // A-frag offset in slot
  const int bR = 4 * (lane >> 4);                         // group-row base for acc rows

  float c[4] = {0.f, 0.f, 0.f, 0.f};

  for (int t = 0; t < Tlen; ++t) {
    // ---- phase 1: cross-layer input ----
    f32x4 acc0 = {bias0, bias0, bias0, bias0};
    f32x4 acc1 = {bias1, bias1, bias1, bias1};
    if (layer > 0) {
      wait_multi(flagsP + (lane & 15), (uint32_t)(t + 1));
      const short* xin = ringPG + (t & (RING - 1)) * (16 * Hdim);
      short8 ap[16];
#pragma unroll
      for (int ks = 0; ks < 16; ++ks) ap[ks] = ring_ld16(xin + aoff + ks * 32);
#pragma unroll
      for (int ks = 0; ks < 16; ++ks) {
        acc0 = mfma16(ap[ks], bw[ks][0], acc0);
        acc1 = mfma16(ap[ks], bw[ks][1], acc1);
      }
    } else if (t > 0) {
#pragma unroll
      for (int r = 0; r < 4; ++r) {
        float xv = x[(g * 16 + bR + r) * Tlen + (t - 1)];  // DELAY=1
        acc0[r] += xw0 * xv;
        acc1[r] += xw1 * xv;
      }
    }

    // ---- phase 2: own-layer recurrence (merged own + backpressure poll) ----
    {
      uint32_t tgt;
      if (pollMode == 0) tgt = (uint32_t)t;
      else if (pollMode == 1) tgt = (t + 1 >= RING) ? (uint32_t)(t + 1 - RING) : 0u;
      else tgt = 0u;
      wait_multi(pollP2, tgt);
    }

    if (t > 0) {
      const short* hin = ringLG + ((t - 1) & (RING - 1)) * (16 * Hdim);
      short8 ar[16];
#pragma unroll
      for (int ks = 0; ks < 16; ++ks) ar[ks] = ring_ld16(hin + aoff + ks * 32);
      if (layer == 0) {
#pragma unroll
        for (int ks = 0; ks < 16; ++ks) {
          acc0 = mfma16(ar[ks], bw[ks][0], acc0);
          acc1 = mfma16(ar[ks], bw[ks][1], acc1);
        }
      } else {
#pragma unroll
        for (int ks = 0; ks < 16; ++ks) {
          acc0 = mfma16(ar[ks], bw[16 + ks][0], acc0);
          acc1 = mfma16(ar[ks], bw[16 + ks][1], acc1);
        }
      }
    }

    // ---- activations / state update ----
    float parts[4];
#pragma unroll
    for (int r = 0; r < 4; ++r) {
      float a0 = acc0[r], a1 = acc1[r];
      float p0 = __shfl_xor(a0, 8);
      float p1 = __shfl_xor(a1, 8);
      float iv = 1.f / (1.f + __expf(-a0));
      float fv = 1.f / (1.f + __expf(-p0));
      float gv = tanhf(a1);
      float ov = 1.f / (1.f + __expf(-p1));
      c[r] = fv * c[r] + iv * gv;
      float hv = ov * tanhf(c[r]);
      if ((lane & 8) == 0) hbuf[bR + r][wave * 8 + (lane & 7)] = f2bf(hv);
      parts[r] = hv * woutd;
    }
    if (layer == 2) {
#pragma unroll
      for (int r = 0; r < 4; ++r) {
        parts[r] += __shfl_xor(parts[r], 1);
        parts[r] += __shfl_xor(parts[r], 2);
        parts[r] += __shfl_xor(parts[r], 4);
        if ((lane & 15) == 0) pbuf[wave][bR + r] = parts[r];
      }
    }

    // ---- publish h (wave 0) + flag, THEN out-head off critical path ----
    __syncthreads();  // hbuf (+ pbuf) complete
    if (wave == 0) {
      short* hout = ringLG + (t & (RING - 1)) * (16 * Hdim);
      int row = lane >> 2, q = lane & 3;
      u64x2 u;
      u.lo = ((const u64*)&hbuf[row][q * 8])[0];
      u.hi = ((const u64*)&hbuf[row][q * 8])[1];
      u64* dst = (u64*)(hout + row * Hdim + d * 32 + q * 8);
      __hip_atomic_store(dst,     u.lo, __ATOMIC_RELAXED, __HIP_MEMORY_SCOPE_AGENT);
      __hip_atomic_store(dst + 1, u.hi, __ATOMIC_RELAXED, __HIP_MEMORY_SCOPE_AGENT);
      vm_wait0();  // h stores at coherence point before flag
      if (lane == 0)
        __hip_atomic_store(flagsO + d, (uint32_t)(t + 1), __ATOMIC_RELAXED,
                           __HIP_MEMORY_SCOPE_AGENT);
      if (layer == 2 && lane < 16) {
        float s = pbuf[0][lane] + pbuf[1][lane] + pbuf[2][lane] + pbuf[3][lane];
        atomicAdd(out + (g * 16 + lane) * Tlen + t, s);
      }
    }
    __syncthreads();  // protect hbuf/pbuf reuse next step
  }
}

extern "C" void kernel_launch(void* const* d_in, const int* in_sizes, int n_in,
                              void* d_out, int out_size, void* d_ws, size_t ws_size,
                              hipStream_t stream) {
  const float* x    = (const float*)d_in[0];
  const float* Wih0 = (const float*)d_in[1];
  const float* Whh0 = (const float*)d_in[2];
  const float* bih0 = (const float*)d_in[3];
  const float* bhh0 = (const float*)d_in[4];
  const float* Wih1 = (const float*)d_in[5];
  const float* Whh1 = (const float*)d_in[6];
  const float* bih1 = (const float*)d_in[7];
  const float* bhh1 = (const float*)d_in[8];
  const float* Wih2 = (const float*)d_in[9];
  const float* Whh2 = (const float*)d_in[10];
  const float* bih2 = (const float*)d_in[11];
  const float* bhh2 = (const float*)d_in[12];
  const float* Wout = (const float*)d_in[13];
  const float* bout = (const float*)d_in[14];

  char* ws = (char*)d_ws;
  short* Bpack    = (short*)ws;                          // 10,485,760 B
  short* rings    = (short*)(ws + 10485760);             // 3*4*RING*16*512*2 = 1,572,864 B
  uint32_t* flags = (uint32_t*)(ws + 12058624);          // 3*4*32*4 = 1536 B
  float* out      = (float*)d_out;

  hipMemsetAsync(flags, 0, 3 * 4 * 32 * sizeof(uint32_t), stream);
  out_init<<<(Bsz * Tlen + 255) / 256, 256, 0, stream>>>(out, bout);
  pack_kernel<<<2560, 256, 0, stream>>>(Whh0, Wih1, Whh1, Wih2, Whh2, Bpack);
  lstm_persist<<<192, 256, 0, stream>>>(x, Wih0, bih0, bhh0, bih1, bhh1, bih2, bhh2,
                                        Wout, Bpack, rings, flags, out);
}

// Round 7
// 10041.878 us; speedup vs baseline: 1.9325x; 1.0189x over previous
//
#include <hip/hip_runtime.h>
#include <stdint.h>

#define Hdim 512
#define Bsz 64
#define Tlen 1024
#define RING 8
#define GR (RING * 16 * Hdim)  // ring shorts per (layer,group)
#define FSTR 16                // flag stride in words (one flag per 64-B line)

typedef __attribute__((ext_vector_type(8))) short short8;
typedef __attribute__((ext_vector_type(4))) float f32x4;
typedef unsigned long long u64;
struct u64x2 { u64 lo, hi; };

__device__ __forceinline__ short f2bf(float f) {
  uint32_t u = __float_as_uint(f);
  u += 0x7fffu + ((u >> 16) & 1u);   // RNE
  return (short)(u >> 16);
}

__device__ __forceinline__ f32x4 mfma16(short8 a, short8 b, f32x4 c) {
  return __builtin_amdgcn_mfma_f32_16x16x32_bf16(a, b, c, 0, 0, 0);
}

// LLC-coherent 16B ring read as two relaxed agent-scope 8B atomic loads (R5-proven).
__device__ __forceinline__ short8 ring_ld16(const short* p) {
  u64x2 u;
  u.lo = __hip_atomic_load((const u64*)p,     __ATOMIC_RELAXED, __HIP_MEMORY_SCOPE_AGENT);
  u.hi = __hip_atomic_load((const u64*)p + 1, __ATOMIC_RELAXED, __HIP_MEMORY_SCOPE_AGENT);
  return __builtin_bit_cast(short8, u);
}

__device__ __forceinline__ void vm_wait0() {
  asm volatile("s_waitcnt vmcnt(0)" ::: "memory");
  __builtin_amdgcn_sched_barrier(0);
}

// Poll (wave 0 only): lane watches *pp (per-lane addr & target) with backoff.
__device__ __forceinline__ void wait_multi(const uint32_t* pp, uint32_t tgt) {
  uint32_t it = 0;
  for (;;) {
    uint32_t v = __hip_atomic_load(pp, __ATOMIC_RELAXED, __HIP_MEMORY_SCOPE_AGENT);
    if (__all((int)(v >= tgt))) break;
    __builtin_amdgcn_s_sleep(1);  // ~64 cyc backoff: cuts same-line poll pressure
    if (++it > (1u << 20)) break; // failsafe against hang
  }
}

__global__ void out_init(float* out, const float* bout) {
  int i = blockIdx.x * 256 + threadIdx.x;
  if (i < Bsz * Tlen) out[i] = bout[0];
}

// ---- weight pack: unchanged from R6 (verified correct) ----
__global__ void pack_kernel(const float* __restrict__ Whh0,
                            const float* __restrict__ Wih1, const float* __restrict__ Whh1,
                            const float* __restrict__ Wih2, const float* __restrict__ Whh2,
                            short* __restrict__ Bpack) {
  int ch = blockIdx.x * 256 + threadIdx.x;
  const int L0C = 64 * 16 * 2 * 64;
  const int L12C = 64 * 32 * 2 * 64;
  if (ch >= L0C + 2 * L12C) return;
  int layer, rel, KS;
  const float* Wih;
  const float* Whh;
  if (ch < L0C) { layer = 0; rel = ch; KS = 16; Wih = nullptr; Whh = Whh0; }
  else if (ch < L0C + L12C) { layer = 1; rel = ch - L0C; KS = 32; Wih = Wih1; Whh = Whh1; }
  else { layer = 2; rel = ch - L0C - L12C; KS = 32; Wih = Wih2; Whh = Whh2; }
  int lane = rel & 63;
  int nt = (rel >> 6) & 1;
  int rest = rel >> 7;          // (d*4+w)*KS + ks
  int ks = rest % KS;
  int dw = rest / KS;
  int w = dw & 3;
  int d = dw >> 2;
  int col = nt * 16 + (lane & 15);
  int row = (col >> 3) * Hdim + d * 32 + w * 8 + (col & 7);
  int kbase = ks * 32 + (lane >> 4) * 8;
  short8 v;
#pragma unroll
  for (int e = 0; e < 8; ++e) {
    int k = kbase + e;
    float wt;
    if (layer == 0) wt = Whh[row * Hdim + k];
    else wt = (k < Hdim) ? Wih[row * Hdim + k] : Whh[row * Hdim + (k - Hdim)];
    v[e] = f2bf(wt);
  }
  ((short8*)Bpack)[ch] = v;
}

__global__ __launch_bounds__(256, 1)
void lstm_persist(const float* __restrict__ x,
                  const float* __restrict__ Wih0v,
                  const float* __restrict__ bih0, const float* __restrict__ bhh0,
                  const float* __restrict__ bih1, const float* __restrict__ bhh1,
                  const float* __restrict__ bih2, const float* __restrict__ bhh2,
                  const float* __restrict__ Wout,
                  const short* __restrict__ Bpack,
                  short* __restrict__ rings,
                  uint32_t* __restrict__ flags,
                  float* __restrict__ out) {
  const int blk = blockIdx.x;
  const int layer = blk >> 6;          // 0..2
  const int g = (blk >> 4) & 3;        // batch group (16 rows)
  const int d = blk & 15;              // dim-block (32 h-dims)
  const int tid = threadIdx.x;
  const int lane = tid & 63;
  const int wave = tid >> 6;           // 0..3 = N-slice (8 h-dims, 4 gates)

  __shared__ short hbuf[16][32];       // [group-row][dim within block]
  __shared__ float pbuf[4][16];        // out-head partials [wave][group-row]

  // ---- persistent B fragments: plain loads + keepalive pin (R4/R5/R6-proven) ----
  short8 bw[32][2];
  {
    const short8* bp = (const short8*)Bpack;
    if (layer == 0) {
#pragma unroll
      for (int ks = 0; ks < 16; ++ks) {
        bw[ks][0] = bp[((((d * 4 + wave) * 16 + ks) * 2 + 0) * 64) + lane];
        bw[ks][1] = bp[((((d * 4 + wave) * 16 + ks) * 2 + 1) * 64) + lane];
        asm volatile("" : "+v"(bw[ks][0]), "+v"(bw[ks][1]));
      }
    } else {
      const int base = (layer == 1) ? 131072 : 393216;
#pragma unroll
      for (int ks = 0; ks < 32; ++ks) {
        bw[ks][0] = bp[base + (((d * 4 + wave) * 32 + ks) * 2 + 0) * 64 + lane];
        bw[ks][1] = bp[base + (((d * 4 + wave) * 32 + ks) * 2 + 1) * 64 + lane];
        asm volatile("" : "+v"(bw[ks][0]), "+v"(bw[ks][1]));
      }
    }
  }

  const float* bih = (layer == 0) ? bih0 : (layer == 1 ? bih1 : bih2);
  const float* bhh = (layer == 0) ? bhh0 : (layer == 1 ? bhh1 : bhh2);
  const int dimb = d * 32 + wave * 8 + (lane & 7);
  const int row0 = (((lane & 15) >> 3)) * Hdim + dimb;       // gates i/f
  const int row1 = (((lane & 15) >> 3) + 2) * Hdim + dimb;   // gates g/o
  const float bias0 = bih[row0] + bhh[row0];
  const float bias1 = bih[row1] + bhh[row1];
  float xw0 = 0.f, xw1 = 0.f, woutd = 0.f;
  if (layer == 0) { xw0 = Wih0v[row0]; xw1 = Wih0v[row1]; }
  if (layer == 2) woutd = Wout[dimb];

  // flags: one word per 64-B line; 16 lines per (layer,group) domain
  uint32_t* flagsO = flags + ((layer * 4 + g) * 16) * FSTR;
  const uint32_t* flagsP = flags + (((layer - 1) * 4 + g) * 16) * FSTR;  // guarded layer>0
  const uint32_t* flagsN = flags + (((layer + 1) * 4 + g) * 16) * FSTR;  // guarded layer<2
  short* ringLG = rings + (layer * 4 + g) * GR;
  const short* ringPG = rings + ((layer - 1) * 4 + g) * GR;

  // wave-0 poll addresses (per-lane); trivial lanes point at own flag with tgt 0
  const uint32_t* p1ptr = (layer > 0 && lane < 16) ? flagsP + lane * FSTR : flagsO;
  const uint32_t* p2ptr = (lane < 16) ? flagsO + lane * FSTR
                        : (lane < 32 && layer < 2) ? flagsN + (lane - 16) * FSTR : flagsO;
  const bool p2bp = (lane >= 16 && lane < 32 && layer < 2);

  const int aoff = (lane & 15) * Hdim + (lane >> 4) * 8;  // A-frag offset in slot
  const int bR = 4 * (lane >> 4);                         // group-row base for acc rows

  float c[4] = {0.f, 0.f, 0.f, 0.f};

  for (int t = 0; t < Tlen; ++t) {
    // ---- phase 1: cross-layer input ----
    if (layer > 0) {
      if (wave == 0) {
        uint32_t tgt1 = (lane < 16) ? (uint32_t)(t + 1) : 0u;
        wait_multi(p1ptr, tgt1);
      }
      __syncthreads();  // release all waves once wave 0 confirmed
    }

    f32x4 acc0 = {bias0, bias0, bias0, bias0};
    f32x4 acc1 = {bias1, bias1, bias1, bias1};
    if (layer > 0) {
      const short* xin = ringPG + (t & (RING - 1)) * (16 * Hdim);
      short8 ap[16];
#pragma unroll
      for (int ks = 0; ks < 16; ++ks) ap[ks] = ring_ld16(xin + aoff + ks * 32);
#pragma unroll
      for (int ks = 0; ks < 16; ++ks) {
        acc0 = mfma16(ap[ks], bw[ks][0], acc0);
        acc1 = mfma16(ap[ks], bw[ks][1], acc1);
      }
    } else if (t > 0) {
#pragma unroll
      for (int r = 0; r < 4; ++r) {
        float xv = x[(g * 16 + bR + r) * Tlen + (t - 1)];  // DELAY=1
        acc0[r] += xw0 * xv;
        acc1[r] += xw1 * xv;
      }
    }

    // ---- phase 2: own-layer recurrence (wave-0 poll: own + backpressure) ----
    if (wave == 0) {
      uint32_t tgt2;
      if (lane < 16) tgt2 = (uint32_t)t;
      else if (p2bp) tgt2 = (t + 1 >= RING) ? (uint32_t)(t + 1 - RING) : 0u;
      else tgt2 = 0u;
      wait_multi(p2ptr, tgt2);
    }
    __syncthreads();

    if (t > 0) {
      const short* hin = ringLG + ((t - 1) & (RING - 1)) * (16 * Hdim);
      short8 ar[16];
#pragma unroll
      for (int ks = 0; ks < 16; ++ks) ar[ks] = ring_ld16(hin + aoff + ks * 32);
      if (layer == 0) {
#pragma unroll
        for (int ks = 0; ks < 16; ++ks) {
          acc0 = mfma16(ar[ks], bw[ks][0], acc0);
          acc1 = mfma16(ar[ks], bw[ks][1], acc1);
        }
      } else {
#pragma unroll
        for (int ks = 0; ks < 16; ++ks) {
          acc0 = mfma16(ar[ks], bw[16 + ks][0], acc0);
          acc1 = mfma16(ar[ks], bw[16 + ks][1], acc1);
        }
      }
    }

    // ---- activations / state update ----
    float parts[4];
#pragma unroll
    for (int r = 0; r < 4; ++r) {
      float a0 = acc0[r], a1 = acc1[r];
      float p0 = __shfl_xor(a0, 8);
      float p1 = __shfl_xor(a1, 8);
      float iv = 1.f / (1.f + __expf(-a0));
      float fv = 1.f / (1.f + __expf(-p0));
      float gv = tanhf(a1);
      float ov = 1.f / (1.f + __expf(-p1));
      c[r] = fv * c[r] + iv * gv;
      float hv = ov * tanhf(c[r]);
      if ((lane & 8) == 0) hbuf[bR + r][wave * 8 + (lane & 7)] = f2bf(hv);
      parts[r] = hv * woutd;
    }
    if (layer == 2) {
#pragma unroll
      for (int r = 0; r < 4; ++r) {
        parts[r] += __shfl_xor(parts[r], 1);
        parts[r] += __shfl_xor(parts[r], 2);
        parts[r] += __shfl_xor(parts[r], 4);
        if ((lane & 15) == 0) pbuf[wave][bR + r] = parts[r];
      }
    }

    // ---- publish h (wave 0) + flag; out-head after flag ----
    __syncthreads();  // hbuf (+ pbuf) complete
    if (wave == 0) {
      short* hout = ringLG + (t & (RING - 1)) * (16 * Hdim);
      int row = lane >> 2, q = lane & 3;
      u64x2 u;
      u.lo = ((const u64*)&hbuf[row][q * 8])[0];
      u.hi = ((const u64*)&hbuf[row][q * 8])[1];
      u64* dst = (u64*)(hout + row * Hdim + d * 32 + q * 8);
      __hip_atomic_store(dst,     u.lo, __ATOMIC_RELAXED, __HIP_MEMORY_SCOPE_AGENT);
      __hip_atomic_store(dst + 1, u.hi, __ATOMIC_RELAXED, __HIP_MEMORY_SCOPE_AGENT);
      vm_wait0();  // h stores at coherence point before flag
      if (lane == 0)
        __hip_atomic_store(flagsO + d * FSTR, (uint32_t)(t + 1), __ATOMIC_RELAXED,
                           __HIP_MEMORY_SCOPE_AGENT);
      if (layer == 2 && lane < 16) {
        float s = pbuf[0][lane] + pbuf[1][lane] + pbuf[2][lane] + pbuf[3][lane];
        atomicAdd(out + (g * 16 + lane) * Tlen + t, s);
      }
    }
    // no trailing barrier: wave 0 finished reading hbuf/pbuf before it can pass
    // the next iteration's phase barriers; other waves write hbuf only after those.
  }
}

extern "C" void kernel_launch(void* const* d_in, const int* in_sizes, int n_in,
                              void* d_out, int out_size, void* d_ws, size_t ws_size,
                              hipStream_t stream) {
  const float* x    = (const float*)d_in[0];
  const float* Wih0 = (const float*)d_in[1];
  const float* Whh0 = (const float*)d_in[2];
  const float* bih0 = (const float*)d_in[3];
  const float* bhh0 = (const float*)d_in[4];
  const float* Wih1 = (const float*)d_in[5];
  const float* Whh1 = (const float*)d_in[6];
  const float* bih1 = (const float*)d_in[7];
  const float* bhh1 = (const float*)d_in[8];
  const float* Wih2 = (const float*)d_in[9];
  const float* Whh2 = (const float*)d_in[10];
  const float* bih2 = (const float*)d_in[11];
  const float* bhh2 = (const float*)d_in[12];
  const float* Wout = (const float*)d_in[13];
  const float* bout = (const float*)d_in[14];

  char* ws = (char*)d_ws;
  short* Bpack    = (short*)ws;                          // 10,485,760 B
  short* rings    = (short*)(ws + 10485760);             // 1,572,864 B
  uint32_t* flags = (uint32_t*)(ws + 12058624);          // 12*16*16*4 = 12,288 B
  float* out      = (float*)d_out;

  hipMemsetAsync(flags, 0, 12 * 16 * FSTR * sizeof(uint32_t), stream);
  out_init<<<(Bsz * Tlen + 255) / 256, 256, 0, stream>>>(out, bout);
  pack_kernel<<<2560, 256, 0, stream>>>(Whh0, Wih1, Whh1, Wih2, Whh2, Bpack);
  lstm_persist<<<192, 256, 0, stream>>>(x, Wih0, bih0, bhh0, bih1, bhh1, bih2, bhh2,
                                        Wout, Bpack, rings, flags, out);
}

// Round 10
// 5845.737 us; speedup vs baseline: 3.3197x; 1.7178x over previous
//
#include <hip/hip_runtime.h>
#include <stdint.h>

#define Hdim 512
#define Bsz 64
#define Tlen 1024
#define RING 8
#define GR (RING * 16 * Hdim)  // ring shorts per (layer,group)
#define FSTR 16                // flag stride in words (one flag per 64-B line)
#define LROW 516               // shorts per LDS-staged row (512 + 4 pad -> 1032 B stride)

typedef __attribute__((ext_vector_type(8))) short short8;
typedef __attribute__((ext_vector_type(4))) short bf16x4;
typedef __attribute__((ext_vector_type(4))) float f32x4;
typedef unsigned long long u64;
struct u64x2 { u64 lo, hi; };

__device__ __forceinline__ short f2bf(float f) {
  uint32_t u = __float_as_uint(f);
  u += 0x7fffu + ((u >> 16) & 1u);   // RNE
  return (short)(u >> 16);
}

__device__ __forceinline__ f32x4 mfma16(short8 a, short8 b, f32x4 c) {
  return __builtin_amdgcn_mfma_f32_16x16x32_bf16(a, b, c, 0, 0, 0);
}

__device__ __forceinline__ void vm_wait0() {
  asm volatile("s_waitcnt vmcnt(0)" ::: "memory");
  __builtin_amdgcn_sched_barrier(0);
}

// Poll (wave 0 only): lane watches *pp (per-lane addr & target) with backoff.
__device__ __forceinline__ void wait_multi(const uint32_t* pp, uint32_t tgt) {
  uint32_t it = 0;
  for (;;) {
    uint32_t v = __hip_atomic_load(pp, __ATOMIC_RELAXED, __HIP_MEMORY_SCOPE_AGENT);
    if (__all((int)(v >= tgt))) break;
    __builtin_amdgcn_s_sleep(1);
    if (++it > (1u << 20)) break; // failsafe against hang
  }
}

// Cooperative stage: 16x512 ring slot (row stride 512 shorts) -> LDS (row stride LROW).
// Wave w stages rows w*4..w*4+3. Each row = 128 u64 chunks; lane l copies chunks
// l and l+64 (R9 bug: copied only chunk l -> half-row garbage -> NaN).
__device__ __forceinline__ void stage_slot(const short* __restrict__ src,
                                           short* __restrict__ lds,
                                           int wave, int lane) {
#pragma unroll
  for (int j = 0; j < 4; ++j) {
    int r = wave * 4 + j;
    const u64* s = (const u64*)(src + r * 512);
    u64* dst = (u64*)(lds + r * LROW);
    u64 v0 = __hip_atomic_load(s + lane,      __ATOMIC_RELAXED, __HIP_MEMORY_SCOPE_AGENT);
    u64 v1 = __hip_atomic_load(s + lane + 64, __ATOMIC_RELAXED, __HIP_MEMORY_SCOPE_AGENT);
    dst[lane]      = v0;
    dst[lane + 64] = v1;
  }
}

// MFMA A-fragment from staged LDS: row = lane&15, dims [(lane>>4)*8 + ks*32, +8)
__device__ __forceinline__ short8 frag_read(const short* __restrict__ lds,
                                            int lane, int ks) {
  int base = (lane & 15) * LROW + (lane >> 4) * 8 + ks * 32;
  bf16x4 lo = *(const bf16x4*)(lds + base);
  bf16x4 hi = *(const bf16x4*)(lds + base + 4);
  short8 r;
  r[0] = lo[0]; r[1] = lo[1]; r[2] = lo[2]; r[3] = lo[3];
  r[4] = hi[0]; r[5] = hi[1]; r[6] = hi[2]; r[7] = hi[3];
  return r;
}

__global__ void out_init(float* out, const float* bout) {
  int i = blockIdx.x * 256 + threadIdx.x;
  if (i < Bsz * Tlen) out[i] = bout[0];
}

// ---- weight pack: unchanged from R6/R7 (verified correct) ----
__global__ void pack_kernel(const float* __restrict__ Whh0,
                            const float* __restrict__ Wih1, const float* __restrict__ Whh1,
                            const float* __restrict__ Wih2, const float* __restrict__ Whh2,
                            short* __restrict__ Bpack) {
  int ch = blockIdx.x * 256 + threadIdx.x;
  const int L0C = 64 * 16 * 2 * 64;
  const int L12C = 64 * 32 * 2 * 64;
  if (ch >= L0C + 2 * L12C) return;
  int layer, rel, KS;
  const float* Wih;
  const float* Whh;
  if (ch < L0C) { layer = 0; rel = ch; KS = 16; Wih = nullptr; Whh = Whh0; }
  else if (ch < L0C + L12C) { layer = 1; rel = ch - L0C; KS = 32; Wih = Wih1; Whh = Whh1; }
  else { layer = 2; rel = ch - L0C - L12C; KS = 32; Wih = Wih2; Whh = Whh2; }
  int lane = rel & 63;
  int nt = (rel >> 6) & 1;
  int rest = rel >> 7;          // (d*4+w)*KS + ks
  int ks = rest % KS;
  int dw = rest / KS;
  int w = dw & 3;
  int d = dw >> 2;
  int col = nt * 16 + (lane & 15);
  int row = (col >> 3) * Hdim + d * 32 + w * 8 + (col & 7);
  int kbase = ks * 32 + (lane >> 4) * 8;
  short8 v;
#pragma unroll
  for (int e = 0; e < 8; ++e) {
    int k = kbase + e;
    float wt;
    if (layer == 0) wt = Whh[row * Hdim + k];
    else wt = (k < Hdim) ? Wih[row * Hdim + k] : Whh[row * Hdim + (k - Hdim)];
    v[e] = f2bf(wt);
  }
  ((short8*)Bpack)[ch] = v;
}

__global__ __launch_bounds__(256, 1)
void lstm_persist(const float* __restrict__ x,
                  const float* __restrict__ Wih0v,
                  const float* __restrict__ bih0, const float* __restrict__ bhh0,
                  const float* __restrict__ bih1, const float* __restrict__ bhh1,
                  const float* __restrict__ bih2, const float* __restrict__ bhh2,
                  const float* __restrict__ Wout,
                  const short* __restrict__ Bpack,
                  short* __restrict__ rings,
                  uint32_t* __restrict__ flags,
                  float* __restrict__ out) {
  const int blk = blockIdx.x;
  const int layer = blk >> 6;          // 0..2
  const int g = (blk >> 4) & 3;        // batch group (16 rows)
  const int d = blk & 15;              // dim-block (32 h-dims)
  const int tid = threadIdx.x;
  const int lane = tid & 63;
  const int wave = tid >> 6;           // 0..3 = N-slice (8 h-dims, 4 gates)

  __shared__ short ldsA[16 * LROW];    // staged prev-layer h (phase 1)
  __shared__ short ldsB[16 * LROW];    // staged own-layer h (phase 2)
  __shared__ short hbuf[16][32];       // [group-row][dim within block]
  __shared__ float pbuf[4][16];        // out-head partials [wave][group-row]

  // ---- persistent B fragments: plain loads + keepalive pin (R4-R7-proven) ----
  short8 bw[32][2];
  {
    const short8* bp = (const short8*)Bpack;
    if (layer == 0) {
#pragma unroll
      for (int ks = 0; ks < 16; ++ks) {
        bw[ks][0] = bp[((((d * 4 + wave) * 16 + ks) * 2 + 0) * 64) + lane];
        bw[ks][1] = bp[((((d * 4 + wave) * 16 + ks) * 2 + 1) * 64) + lane];
        asm volatile("" : "+v"(bw[ks][0]), "+v"(bw[ks][1]));
      }
    } else {
      const int base = (layer == 1) ? 131072 : 393216;
#pragma unroll
      for (int ks = 0; ks < 32; ++ks) {
        bw[ks][0] = bp[base + (((d * 4 + wave) * 32 + ks) * 2 + 0) * 64 + lane];
        bw[ks][1] = bp[base + (((d * 4 + wave) * 32 + ks) * 2 + 1) * 64 + lane];
        asm volatile("" : "+v"(bw[ks][0]), "+v"(bw[ks][1]));
      }
    }
  }

  const float* bih = (layer == 0) ? bih0 : (layer == 1 ? bih1 : bih2);
  const float* bhh = (layer == 0) ? bhh0 : (layer == 1 ? bhh1 : bhh2);
  const int dimb = d * 32 + wave * 8 + (lane & 7);
  const int row0 = (((lane & 15) >> 3)) * Hdim + dimb;       // gates i/f
  const int row1 = (((lane & 15) >> 3) + 2) * Hdim + dimb;   // gates g/o
  const float bias0 = bih[row0] + bhh[row0];
  const float bias1 = bih[row1] + bhh[row1];
  float xw0 = 0.f, xw1 = 0.f, woutd = 0.f;
  if (layer == 0) { xw0 = Wih0v[row0]; xw1 = Wih0v[row1]; }
  if (layer == 2) woutd = Wout[dimb];

  // flags: one word per 64-B line; 16 lines per (layer,group) domain
  uint32_t* flagsO = flags + ((layer * 4 + g) * 16) * FSTR;
  const uint32_t* flagsP = flags + (((layer - 1) * 4 + g) * 16) * FSTR;  // guarded layer>0
  const uint32_t* flagsN = flags + (((layer + 1) * 4 + g) * 16) * FSTR;  // guarded layer<2
  short* ringLG = rings + (layer * 4 + g) * GR;
  const short* ringPG = rings + ((layer - 1) * 4 + g) * GR;

  const uint32_t* p1ptr = (layer > 0 && lane < 16) ? flagsP + lane * FSTR : flagsO;
  const uint32_t* p2ptr = (lane < 16) ? flagsO + lane * FSTR
                        : (lane < 32 && layer < 2) ? flagsN + (lane - 16) * FSTR : flagsO;
  const bool p2bp = (lane >= 16 && lane < 32 && layer < 2);

  const int bR = 4 * (lane >> 4);      // group-row base for acc rows

  float c[4] = {0.f, 0.f, 0.f, 0.f};

  for (int t = 0; t < Tlen; ++t) {
    // ---- phase 1: cross-layer input ----
    f32x4 acc0 = {bias0, bias0, bias0, bias0};
    f32x4 acc1 = {bias1, bias1, bias1, bias1};
    if (layer > 0) {
      if (wave == 0) {
        uint32_t tgt1 = (lane < 16) ? (uint32_t)(t + 1) : 0u;
        wait_multi(p1ptr, tgt1);
      }
      __syncthreads();  // data valid
      stage_slot(ringPG + (t & (RING - 1)) * (16 * Hdim), ldsA, wave, lane);
      __syncthreads();  // staging complete
#pragma unroll
      for (int ks = 0; ks < 16; ++ks) {
        short8 a = frag_read(ldsA, lane, ks);
        acc0 = mfma16(a, bw[ks][0], acc0);
        acc1 = mfma16(a, bw[ks][1], acc1);
      }
    } else if (t > 0) {
#pragma unroll
      for (int r = 0; r < 4; ++r) {
        float xv = x[(g * 16 + bR + r) * Tlen + (t - 1)];  // DELAY=1
        acc0[r] += xw0 * xv;
        acc1[r] += xw1 * xv;
      }
    }

    // ---- phase 2: own-layer recurrence (wave-0 poll: own + backpressure) ----
    if (wave == 0) {
      uint32_t tgt2;
      if (lane < 16) tgt2 = (uint32_t)t;
      else if (p2bp) tgt2 = (t + 1 >= RING) ? (uint32_t)(t + 1 - RING) : 0u;
      else tgt2 = 0u;
      wait_multi(p2ptr, tgt2);
    }
    __syncthreads();

    if (t > 0) {
      stage_slot(ringLG + ((t - 1) & (RING - 1)) * (16 * Hdim), ldsB, wave, lane);
      __syncthreads();  // staging complete
      if (layer == 0) {
#pragma unroll
        for (int ks = 0; ks < 16; ++ks) {
          short8 a = frag_read(ldsB, lane, ks);
          acc0 = mfma16(a, bw[ks][0], acc0);
          acc1 = mfma16(a, bw[ks][1], acc1);
        }
      } else {
#pragma unroll
        for (int ks = 0; ks < 16; ++ks) {
          short8 a = frag_read(ldsB, lane, ks);
          acc0 = mfma16(a, bw[16 + ks][0], acc0);
          acc1 = mfma16(a, bw[16 + ks][1], acc1);
        }
      }
    }

    // ---- activations / state update (R7-identical) ----
    float parts[4];
#pragma unroll
    for (int r = 0; r < 4; ++r) {
      float a0 = acc0[r], a1 = acc1[r];
      float p0 = __shfl_xor(a0, 8);
      float p1 = __shfl_xor(a1, 8);
      float iv = 1.f / (1.f + __expf(-a0));
      float fv = 1.f / (1.f + __expf(-p0));
      float gv = tanhf(a1);
      float ov = 1.f / (1.f + __expf(-p1));
      c[r] = fv * c[r] + iv * gv;
      float hv = ov * tanhf(c[r]);
      if ((lane & 8) == 0) hbuf[bR + r][wave * 8 + (lane & 7)] = f2bf(hv);
      parts[r] = hv * woutd;
    }
    if (layer == 2) {
#pragma unroll
      for (int r = 0; r < 4; ++r) {
        parts[r] += __shfl_xor(parts[r], 1);
        parts[r] += __shfl_xor(parts[r], 2);
        parts[r] += __shfl_xor(parts[r], 4);
        if ((lane & 15) == 0) pbuf[wave][bR + r] = parts[r];
      }
    }

    // ---- publish h (wave 0) + flag; out-head after flag (R7-identical) ----
    __syncthreads();  // hbuf (+ pbuf) complete
    if (wave == 0) {
      short* hout = ringLG + (t & (RING - 1)) * (16 * Hdim);
      int row = lane >> 2, q = lane & 3;
      u64x2 u;
      u.lo = ((const u64*)&hbuf[row][q * 8])[0];
      u.hi = ((const u64*)&hbuf[row][q * 8])[1];
      u64* dst = (u64*)(hout + row * Hdim + d * 32 + q * 8);
      __hip_atomic_store(dst,     u.lo, __ATOMIC_RELAXED, __HIP_MEMORY_SCOPE_AGENT);
      __hip_atomic_store(dst + 1, u.hi, __ATOMIC_RELAXED, __HIP_MEMORY_SCOPE_AGENT);
      vm_wait0();  // h stores at coherence point before flag
      if (lane == 0)
        __hip_atomic_store(flagsO + d * FSTR, (uint32_t)(t + 1), __ATOMIC_RELAXED,
                           __HIP_MEMORY_SCOPE_AGENT);
      if (layer == 2 && lane < 16) {
        float s = pbuf[0][lane] + pbuf[1][lane] + pbuf[2][lane] + pbuf[3][lane];
        atomicAdd(out + (g * 16 + lane) * Tlen + t, s);
      }
    }
    // no trailing barrier needed: wave 0's hbuf reads complete before it passes
    // the next iteration's barriers; other waves rewrite hbuf only after those.
  }
}

extern "C" void kernel_launch(void* const* d_in, const int* in_sizes, int n_in,
                              void* d_out, int out_size, void* d_ws, size_t ws_size,
                              hipStream_t stream) {
  const float* x    = (const float*)d_in[0];
  const float* Wih0 = (const float*)d_in[1];
  const float* Whh0 = (const float*)d_in[2];
  const float* bih0 = (const float*)d_in[3];
  const float* bhh0 = (const float*)d_in[4];
  const float* Wih1 = (const float*)d_in[5];
  const float* Whh1 = (const float*)d_in[6];
  const float* bih1 = (const float*)d_in[7];
  const float* bhh1 = (const float*)d_in[8];
  const float* Wih2 = (const float*)d_in[9];
  const float* Whh2 = (const float*)d_in[10];
  const float* bih2 = (const float*)d_in[11];
  const float* bhh2 = (const float*)d_in[12];
  const float* Wout = (const float*)d_in[13];
  const float* bout = (const float*)d_in[14];

  char* ws = (char*)d_ws;
  short* Bpack    = (short*)ws;                          // 10,485,760 B
  short* rings    = (short*)(ws + 10485760);             // 1,572,864 B
  uint32_t* flags = (uint32_t*)(ws + 12058624);          // 12,288 B (total ~12.07 MB, proven)
  float* out      = (float*)d_out;

  (void)hipMemsetAsync(flags, 0, 12 * 16 * FSTR * sizeof(uint32_t), stream);
  out_init<<<(Bsz * Tlen + 255) / 256, 256, 0, stream>>>(out, bout);
  pack_kernel<<<2560, 256, 0, stream>>>(Whh0, Wih1, Whh1, Wih2, Whh2, Bpack);
  lstm_persist<<<192, 256, 0, stream>>>(x, Wih0, bih0, bhh0, bih1, bhh1, bih2, bhh2,
                                        Wout, Bpack, rings, flags, out);
}

// Round 11
// 5162.540 us; speedup vs baseline: 3.7591x; 1.1323x over previous
//
#include <hip/hip_runtime.h>
#include <stdint.h>

#define Hdim 512
#define Bsz 64
#define Tlen 1024
#define RING 8
#define GR (RING * 16 * Hdim)  // ring shorts per (layer,group)
#define FSTR 16                // flag stride in words (one flag per 64-B line)
#define LROW 516               // shorts per LDS-staged row (512 + 4 pad -> 1032 B stride)

typedef __attribute__((ext_vector_type(8))) short short8;
typedef __attribute__((ext_vector_type(4))) short bf16x4;
typedef __attribute__((ext_vector_type(4))) float f32x4;
typedef unsigned long long u64;
struct u64x2 { u64 lo, hi; };

__device__ __forceinline__ short f2bf(float f) {
  uint32_t u = __float_as_uint(f);
  u += 0x7fffu + ((u >> 16) & 1u);   // RNE
  return (short)(u >> 16);
}

__device__ __forceinline__ f32x4 mfma16(short8 a, short8 b, f32x4 c) {
  return __builtin_amdgcn_mfma_f32_16x16x32_bf16(a, b, c, 0, 0, 0);
}

__device__ __forceinline__ void vm_wait0() {
  asm volatile("s_waitcnt vmcnt(0)" ::: "memory");
  __builtin_amdgcn_sched_barrier(0);
}

// Poll (wave 0 only): lane watches *pp (per-lane addr & target) with backoff.
__device__ __forceinline__ void wait_multi(const uint32_t* pp, uint32_t tgt) {
  uint32_t it = 0;
  for (;;) {
    uint32_t v = __hip_atomic_load(pp, __ATOMIC_RELAXED, __HIP_MEMORY_SCOPE_AGENT);
    if (__all((int)(v >= tgt))) break;
    __builtin_amdgcn_s_sleep(1);
    if (++it > (1u << 20)) break; // failsafe against hang
  }
}

// MFMA A-fragment from staged LDS: row = lane&15, dims [(lane>>4)*8 + ks*32, +8)
__device__ __forceinline__ short8 frag_read(const short* __restrict__ lds,
                                            int lane, int ks) {
  int base = (lane & 15) * LROW + (lane >> 4) * 8 + ks * 32;
  bf16x4 lo = *(const bf16x4*)(lds + base);
  bf16x4 hi = *(const bf16x4*)(lds + base + 4);
  short8 r;
  r[0] = lo[0]; r[1] = lo[1]; r[2] = lo[2]; r[3] = lo[3];
  r[4] = hi[0]; r[5] = hi[1]; r[6] = hi[2]; r[7] = hi[3];
  return r;
}

__global__ void out_init(float* out, const float* bout) {
  int i = blockIdx.x * 256 + threadIdx.x;
  if (i < Bsz * Tlen) out[i] = bout[0];
}

// ---- weight pack: unchanged from R6-R10 (verified correct) ----
__global__ void pack_kernel(const float* __restrict__ Whh0,
                            const float* __restrict__ Wih1, const float* __restrict__ Whh1,
                            const float* __restrict__ Wih2, const float* __restrict__ Whh2,
                            short* __restrict__ Bpack) {
  int ch = blockIdx.x * 256 + threadIdx.x;
  const int L0C = 64 * 16 * 2 * 64;
  const int L12C = 64 * 32 * 2 * 64;
  if (ch >= L0C + 2 * L12C) return;
  int layer, rel, KS;
  const float* Wih;
  const float* Whh;
  if (ch < L0C) { layer = 0; rel = ch; KS = 16; Wih = nullptr; Whh = Whh0; }
  else if (ch < L0C + L12C) { layer = 1; rel = ch - L0C; KS = 32; Wih = Wih1; Whh = Whh1; }
  else { layer = 2; rel = ch - L0C - L12C; KS = 32; Wih = Wih2; Whh = Whh2; }
  int lane = rel & 63;
  int nt = (rel >> 6) & 1;
  int rest = rel >> 7;          // (d*4+w)*KS + ks
  int ks = rest % KS;
  int dw = rest / KS;
  int w = dw & 3;
  int d = dw >> 2;
  int col = nt * 16 + (lane & 15);
  int row = (col >> 3) * Hdim + d * 32 + w * 8 + (col & 7);
  int kbase = ks * 32 + (lane >> 4) * 8;
  short8 v;
#pragma unroll
  for (int e = 0; e < 8; ++e) {
    int k = kbase + e;
    float wt;
    if (layer == 0) wt = Whh[row * Hdim + k];
    else wt = (k < Hdim) ? Wih[row * Hdim + k] : Whh[row * Hdim + (k - Hdim)];
    v[e] = f2bf(wt);
  }
  ((short8*)Bpack)[ch] = v;
}

__global__ __launch_bounds__(256, 1)
void lstm_persist(const float* __restrict__ x,
                  const float* __restrict__ Wih0v,
                  const float* __restrict__ bih0, const float* __restrict__ bhh0,
                  const float* __restrict__ bih1, const float* __restrict__ bhh1,
                  const float* __restrict__ bih2, const float* __restrict__ bhh2,
                  const float* __restrict__ Wout,
                  const short* __restrict__ Bpack,
                  short* __restrict__ rings,
                  uint32_t* __restrict__ flags,
                  float* __restrict__ out) {
  const int blk = blockIdx.x;
  const int layer = blk >> 6;          // 0..2
  const int g = (blk >> 4) & 3;        // batch group (16 rows)
  const int d = blk & 15;              // dim-block (32 h-dims)
  const int tid = threadIdx.x;
  const int lane = tid & 63;
  const int wave = tid >> 6;           // 0..3 = N-slice (8 h-dims, 4 gates)

  __shared__ short ldsA[16 * LROW];    // staged prev-layer h
  __shared__ short ldsB[16 * LROW];    // staged own-layer h
  __shared__ short hbuf[16][32];       // [group-row][dim within block]
  __shared__ float pbuf[4][16];        // out-head partials [wave][group-row]

  // ---- persistent B fragments: plain loads + keepalive pin (R4-R10-proven) ----
  short8 bw[32][2];
  {
    const short8* bp = (const short8*)Bpack;
    if (layer == 0) {
#pragma unroll
      for (int ks = 0; ks < 16; ++ks) {
        bw[ks][0] = bp[((((d * 4 + wave) * 16 + ks) * 2 + 0) * 64) + lane];
        bw[ks][1] = bp[((((d * 4 + wave) * 16 + ks) * 2 + 1) * 64) + lane];
        asm volatile("" : "+v"(bw[ks][0]), "+v"(bw[ks][1]));
      }
    } else {
      const int base = (layer == 1) ? 131072 : 393216;
#pragma unroll
      for (int ks = 0; ks < 32; ++ks) {
        bw[ks][0] = bp[base + (((d * 4 + wave) * 32 + ks) * 2 + 0) * 64 + lane];
        bw[ks][1] = bp[base + (((d * 4 + wave) * 32 + ks) * 2 + 1) * 64 + lane];
        asm volatile("" : "+v"(bw[ks][0]), "+v"(bw[ks][1]));
      }
    }
  }

  const float* bih = (layer == 0) ? bih0 : (layer == 1 ? bih1 : bih2);
  const float* bhh = (layer == 0) ? bhh0 : (layer == 1 ? bhh1 : bhh2);
  const int dimb = d * 32 + wave * 8 + (lane & 7);
  const int row0 = (((lane & 15) >> 3)) * Hdim + dimb;       // gates i/f
  const int row1 = (((lane & 15) >> 3) + 2) * Hdim + dimb;   // gates g/o
  const float bias0 = bih[row0] + bhh[row0];
  const float bias1 = bih[row1] + bhh[row1];
  float xw0 = 0.f, xw1 = 0.f, woutd = 0.f;
  if (layer == 0) { xw0 = Wih0v[row0]; xw1 = Wih0v[row1]; }
  if (layer == 2) woutd = Wout[dimb];

  // flags: one word per 64-B line; 16 lines per (layer,group) domain
  uint32_t* flagsO = flags + ((layer * 4 + g) * 16) * FSTR;
  const uint32_t* flagsP = flags + (((layer - 1) * 4 + g) * 16) * FSTR;  // guarded layer>0
  const uint32_t* flagsN = flags + (((layer + 1) * 4 + g) * 16) * FSTR;  // guarded layer<2
  short* ringLG = rings + (layer * 4 + g) * GR;
  const short* ringPG = rings + ((layer - 1) * 4 + g) * GR;

  // Combined-poll per-lane assignment (wave 0 only):
  //   lanes  0-15: own flags, tgt t        (own h(t-1) ready)
  //   lanes 16-31: prev flags, tgt t+1     (prev h(t) ready)        [layer>0]
  //   lanes 32-47: next flags, tgt t+1-RING (ring slot free)        [layer<2]
  const uint32_t* pptr;
  int pmode;  // 0=own, 1=prev, 2=backpressure, 3=trivial
  if (lane < 16) { pptr = flagsO + lane * FSTR; pmode = 0; }
  else if (lane < 32 && layer > 0) { pptr = flagsP + (lane - 16) * FSTR; pmode = 1; }
  else if (lane >= 32 && lane < 48 && layer < 2) { pptr = flagsN + (lane - 32) * FSTR; pmode = 2; }
  else { pptr = flagsO; pmode = 3; }

  const int bR = 4 * (lane >> 4);      // group-row base for acc rows

  float c[4] = {0.f, 0.f, 0.f, 0.f};

  for (int t = 0; t < Tlen; ++t) {
    // ---- single combined wait (wave 0) ----
    if (wave == 0) {
      uint32_t tgt;
      if (pmode == 0) tgt = (uint32_t)t;
      else if (pmode == 1) tgt = (uint32_t)(t + 1);
      else if (pmode == 2) tgt = (t + 1 >= RING) ? (uint32_t)(t + 1 - RING) : 0u;
      else tgt = 0u;
      wait_multi(pptr, tgt);
    }
    __syncthreads();

    // ---- single staging burst: both slots, loads issued before stores ----
    {
      const bool doA = (layer > 0);
      const bool doB = (t > 0);
      u64 va[8], vb[8];
      if (doA) {
        const short* srcA = ringPG + (t & (RING - 1)) * (16 * Hdim);
#pragma unroll
        for (int j = 0; j < 4; ++j) {
          const u64* s = (const u64*)(srcA + (wave * 4 + j) * 512);
          va[2 * j]     = __hip_atomic_load(s + lane,      __ATOMIC_RELAXED, __HIP_MEMORY_SCOPE_AGENT);
          va[2 * j + 1] = __hip_atomic_load(s + lane + 64, __ATOMIC_RELAXED, __HIP_MEMORY_SCOPE_AGENT);
        }
      }
      if (doB) {
        const short* srcB = ringLG + ((t - 1) & (RING - 1)) * (16 * Hdim);
#pragma unroll
        for (int j = 0; j < 4; ++j) {
          const u64* s = (const u64*)(srcB + (wave * 4 + j) * 512);
          vb[2 * j]     = __hip_atomic_load(s + lane,      __ATOMIC_RELAXED, __HIP_MEMORY_SCOPE_AGENT);
          vb[2 * j + 1] = __hip_atomic_load(s + lane + 64, __ATOMIC_RELAXED, __HIP_MEMORY_SCOPE_AGENT);
        }
      }
      if (doA) {
#pragma unroll
        for (int j = 0; j < 4; ++j) {
          u64* dst = (u64*)(ldsA + (wave * 4 + j) * LROW);
          dst[lane]      = va[2 * j];
          dst[lane + 64] = va[2 * j + 1];
        }
      }
      if (doB) {
#pragma unroll
        for (int j = 0; j < 4; ++j) {
          u64* dst = (u64*)(ldsB + (wave * 4 + j) * LROW);
          dst[lane]      = vb[2 * j];
          dst[lane + 64] = vb[2 * j + 1];
        }
      }
    }
    __syncthreads();

    // ---- all MFMA back-to-back ----
    f32x4 acc0 = {bias0, bias0, bias0, bias0};
    f32x4 acc1 = {bias1, bias1, bias1, bias1};
    if (layer > 0) {
#pragma unroll
      for (int ks = 0; ks < 16; ++ks) {
        short8 a = frag_read(ldsA, lane, ks);
        acc0 = mfma16(a, bw[ks][0], acc0);
        acc1 = mfma16(a, bw[ks][1], acc1);
      }
    } else if (t > 0) {
#pragma unroll
      for (int r = 0; r < 4; ++r) {
        float xv = x[(g * 16 + bR + r) * Tlen + (t - 1)];  // DELAY=1
        acc0[r] += xw0 * xv;
        acc1[r] += xw1 * xv;
      }
    }
    if (t > 0) {
      if (layer == 0) {
#pragma unroll
        for (int ks = 0; ks < 16; ++ks) {
          short8 a = frag_read(ldsB, lane, ks);
          acc0 = mfma16(a, bw[ks][0], acc0);
          acc1 = mfma16(a, bw[ks][1], acc1);
        }
      } else {
#pragma unroll
        for (int ks = 0; ks < 16; ++ks) {
          short8 a = frag_read(ldsB, lane, ks);
          acc0 = mfma16(a, bw[16 + ks][0], acc0);
          acc1 = mfma16(a, bw[16 + ks][1], acc1);
        }
      }
    }

    // ---- activations / state update ----
    float parts[4];
#pragma unroll
    for (int r = 0; r < 4; ++r) {
      float a0 = acc0[r], a1 = acc1[r];
      float p0 = __shfl_xor(a0, 8);
      float p1 = __shfl_xor(a1, 8);
      float iv = 1.f / (1.f + __expf(-a0));
      float fv = 1.f / (1.f + __expf(-p0));
      float gv = tanhf(a1);
      float ov = 1.f / (1.f + __expf(-p1));
      c[r] = fv * c[r] + iv * gv;
      float hv = ov * tanhf(c[r]);
      if ((lane & 8) == 0) hbuf[bR + r][wave * 8 + (lane & 7)] = f2bf(hv);
      parts[r] = hv * woutd;
    }
    if (layer == 2) {
#pragma unroll
      for (int r = 0; r < 4; ++r) {
        parts[r] += __shfl_xor(parts[r], 1);
        parts[r] += __shfl_xor(parts[r], 2);
        parts[r] += __shfl_xor(parts[r], 4);
        if ((lane & 15) == 0) pbuf[wave][bR + r] = parts[r];
      }
    }

    // ---- publish h: 128 u64 chunks split across first 128 threads ----
    __syncthreads();  // hbuf (+ pbuf) complete
    {
      short* hout = ringLG + (t & (RING - 1)) * (16 * Hdim);
      if (tid < 128) {
        int row = tid >> 3, cch = tid & 7;
        u64 v = ((const u64*)&hbuf[row][0])[cch];
        u64* dst = (u64*)(hout + row * Hdim + d * 32) + cch;
        __hip_atomic_store(dst, v, __ATOMIC_RELAXED, __HIP_MEMORY_SCOPE_AGENT);
      }
      vm_wait0();     // own stores acked at coherence point
      __syncthreads();  // ALL publish stores drained
      if (tid == 0)
        __hip_atomic_store(flagsO + d * FSTR, (uint32_t)(t + 1), __ATOMIC_RELAXED,
                           __HIP_MEMORY_SCOPE_AGENT);
      if (layer == 2 && wave == 0 && lane < 16) {
        float s = pbuf[0][lane] + pbuf[1][lane] + pbuf[2][lane] + pbuf[3][lane];
        atomicAdd(out + (g * 16 + lane) * Tlen + t, s);
      }
    }
  }
}

extern "C" void kernel_launch(void* const* d_in, const int* in_sizes, int n_in,
                              void* d_out, int out_size, void* d_ws, size_t ws_size,
                              hipStream_t stream) {
  const float* x    = (const float*)d_in[0];
  const float* Wih0 = (const float*)d_in[1];
  const float* Whh0 = (const float*)d_in[2];
  const float* bih0 = (const float*)d_in[3];
  const float* bhh0 = (const float*)d_in[4];
  const float* Wih1 = (const float*)d_in[5];
  const float* Whh1 = (const float*)d_in[6];
  const float* bih1 = (const float*)d_in[7];
  const float* bhh1 = (const float*)d_in[8];
  const float* Wih2 = (const float*)d_in[9];
  const float* Whh2 = (const float*)d_in[10];
  const float* bih2 = (const float*)d_in[11];
  const float* bhh2 = (const float*)d_in[12];
  const float* Wout = (const float*)d_in[13];
  const float* bout = (const float*)d_in[14];

  char* ws = (char*)d_ws;
  short* Bpack    = (short*)ws;                          // 10,485,760 B
  short* rings    = (short*)(ws + 10485760);             // 1,572,864 B
  uint32_t* flags = (uint32_t*)(ws + 12058624);          // 12,288 B (total ~12.07 MB, proven)
  float* out      = (float*)d_out;

  (void)hipMemsetAsync(flags, 0, 12 * 16 * FSTR * sizeof(uint32_t), stream);
  out_init<<<(Bsz * Tlen + 255) / 256, 256, 0, stream>>>(out, bout);
  pack_kernel<<<2560, 256, 0, stream>>>(Whh0, Wih1, Whh1, Wih2, Whh2, Bpack);
  lstm_persist<<<192, 256, 0, stream>>>(x, Wih0, bih0, bhh0, bih1, bhh1, bih2, bhh2,
                                        Wout, Bpack, rings, flags, out);
}